// Round 7
// baseline (213.342 us; speedup 1.0000x reference)
//
#include <hip/hip_runtime.h>
#include <hip/hip_fp16.h>
#include <math.h>

// GCN forward: h1 = relu(norm_agg(x@W1)+b1); h2 = norm_agg(h1@W2)+b2;
// g = mean_pool(h2, batch); out = g@Wl + bl.
// norm_agg = D^-1/2 (A+I) D^-1/2, CSR-by-dst pull.
// R3: GEMM writes t_scaled[i] = (in@W)[i]*dinv[i] as FP16.
// R4: CSR via 2-pass bucketed counting sort (one block owns each csr line).
// R5: pooling as 4-wave blocks with fused classifier.
// R6: GEMMs use MFMA (fp16 LDS staging, mfma_f32_16x16x32_f16).
// R7: gather tables stored as 32-feature PANELS ([panel][node][32] halves,
//     64B rows, 3.2MB/panel < 4MB XCD L2 -> L2-resident gathers) and the
//     aggregate processes one panel per blockIdx.y pass with 4 edges per
//     wave-load (lane>>4 sub-groups) + shfl_xor combine. gemm1 stages A
//     once and loops both col-tiles (reads x once).

#define FEAT1 128
#define FEAT2 64
#define BCAP 8192   // edge capacity per bucket; avg load = 4096

using half8 = __attribute__((ext_vector_type(8))) _Float16;
using half4 = __attribute__((ext_vector_type(4))) _Float16;
using f32x4 = __attribute__((ext_vector_type(4))) float;

// ---------------- bucketed CSR build ----------------

// pass 1: scatter edges into per-bucket regions, packed src | ((dst&255)<<18)
// bucket_cursor holds RELATIVE fill counts (memset to 0 before launch).
__global__ __launch_bounds__(256) void bin_scatter(const int* __restrict__ esrc,
                                                   const int* __restrict__ edst,
                                                   int ne, int nb,
                                                   int* __restrict__ bucket_cursor,
                                                   int* __restrict__ ebin) {
    __shared__ int lcnt[256];
    __shared__ int lcur[256];
    const int tid = threadIdx.x;
    const int e0 = blockIdx.x * 8192;
    lcnt[tid] = 0;
    __syncthreads();
    #pragma unroll 4
    for (int k = 0; k < 32; k++) {
        int e = e0 + k * 256 + tid;
        if (e < ne) atomicAdd(&lcnt[edst[e] >> 8], 1);
    }
    __syncthreads();
    if (tid < nb && lcnt[tid] > 0)
        lcur[tid] = atomicAdd(&bucket_cursor[tid], lcnt[tid]);
    __syncthreads();
    #pragma unroll 4
    for (int k = 0; k < 32; k++) {
        int e = e0 + k * 256 + tid;
        if (e < ne) {
            int d = edst[e];
            int b = d >> 8;
            int p = atomicAdd(&lcur[b], 1);          // relative position
            if (p < BCAP)                            // capacity guard
                ebin[b * BCAP + p] = esrc[e] | ((d & 255) << 18); // src < 2^17
        }
    }
}

// pass 2: one block per bucket: LDS counts -> scan -> nodeinfo+dinv -> ticket fill
__global__ __launch_bounds__(256) void bucket_csr(const int* __restrict__ ebin,
                                                  const int* __restrict__ bucket_cursor,
                                                  int n_nodes,
                                                  int* __restrict__ csr,
                                                  int2* __restrict__ nodeinfo,
                                                  float* __restrict__ dinv) {
    __shared__ int lcnt[256];
    __shared__ int lscan[256];
    __shared__ int lcur[256];
    const int b = blockIdx.x;
    const int tid = threadIdx.x;
    const int ebeg = b * BCAP;
    int cnt_b = bucket_cursor[b];
    if (cnt_b > BCAP) cnt_b = BCAP;
    const int eend = ebeg + cnt_b;
    lcnt[tid] = 0;
    __syncthreads();
    for (int e = ebeg + tid; e < eend; e += 256)
        atomicAdd(&lcnt[(ebin[e] >> 18) & 255], 1);
    __syncthreads();
    int v = lcnt[tid];
    lscan[tid] = v;
    __syncthreads();
    for (int off = 1; off < 256; off <<= 1) {
        int u = (tid >= off) ? lscan[tid - off] : 0;
        __syncthreads();
        lscan[tid] += u;
        __syncthreads();
    }
    const int start = ebeg + (lscan[tid] - v);   // exclusive scan position
    const int node = (b << 8) + tid;
    if (node < n_nodes) {
        nodeinfo[node] = make_int2(start, v);
        dinv[node] = (float)(1.0 / sqrt((double)(v + 1)));  // +1 self loop
    }
    lcur[tid] = start;
    __syncthreads();
    for (int e = ebeg + tid; e < eend; e += 256) {
        int pk = ebin[e];
        int p = atomicAdd(&lcur[(pk >> 18) & 255], 1);
        csr[p] = pk & 0x3FFFF;
    }
}

// ---------------- MFMA GEMM, fp16+dinv-scaled PANEL output ----------------
// panel(c>>5)[row][c&31] = fp16( (A[row,:128] @ W[:128,c]) * dinv[row] )
// Block: 256 thr = 4 waves; 128 rows; A staged once, inner loop over 64-col
// tiles. Padded LDS stride 136 halves -> b128 fragment reads ~2-way (free).
template <int FOUT, bool A_F16>
__global__ __launch_bounds__(256) void gemm_mfma(const void* __restrict__ Aptr,
                                                 const float* __restrict__ W,
                                                 const float* __restrict__ dinv,
                                                 _Float16* __restrict__ out,
                                                 size_t pstride, int n) {
    __shared__ _Float16 As[128 * 136];
    __shared__ _Float16 Ws[64 * 136];
    const int tid = threadIdx.x;
    const int wv = tid >> 6;
    const int lane = tid & 63;
    constexpr int NCT = FOUT / 64;
    const int row0 = blockIdx.x * 128;

    // stage A: 128 rows x 128 k, 2 threads/row (64 cols each)
    {
        const int r = tid >> 1;
        const int c0 = (tid & 1) * 64;
        const int grow = row0 + r;
        if constexpr (A_F16) {
            const _Float16* A = (const _Float16*)Aptr + (size_t)grow * 128 + c0;
            #pragma unroll
            for (int j = 0; j < 8; j++) {
                half8 v = {};
                if (grow < n) v = *(const half8*)(A + j * 8);
                *(half8*)(&As[r * 136 + c0 + j * 8]) = v;
            }
        } else {
            const float* A = (const float*)Aptr + (size_t)grow * 128 + c0;
            #pragma unroll
            for (int j = 0; j < 16; j++) {
                float4 v = {0.f, 0.f, 0.f, 0.f};
                if (grow < n) v = *(const float4*)(A + j * 4);
                half4 hv = {(_Float16)v.x, (_Float16)v.y, (_Float16)v.z, (_Float16)v.w};
                *(half4*)(&As[r * 136 + c0 + j * 4]) = hv;
            }
        }
    }

    for (int ct = 0; ct < NCT; ct++) {
        const int col0 = ct * 64;
        __syncthreads();   // A ready (iter 0) / Ws reads done (iter >0)
        // stage W transposed: Ws[col][k], 2 threads/k-row (32 cols each)
        {
            const int k = tid >> 1;
            const int cb = (tid & 1) * 32;
            #pragma unroll
            for (int j = 0; j < 8; j++) {
                int c = cb + j * 4;
                float4 v = *(const float4*)(W + (size_t)k * FOUT + col0 + c);
                Ws[(c + 0) * 136 + k] = (_Float16)v.x;
                Ws[(c + 1) * 136 + k] = (_Float16)v.y;
                Ws[(c + 2) * 136 + k] = (_Float16)v.z;
                Ws[(c + 3) * 136 + k] = (_Float16)v.w;
            }
        }
        __syncthreads();

        f32x4 acc[2][4] = {};
        const int mrow = wv * 32 + (lane & 15);
        const int kb = (lane >> 4) * 8;
        #pragma unroll
        for (int ks = 0; ks < 4; ks++) {
            const int kk = ks * 32 + kb;
            half8 a0 = *(const half8*)(&As[mrow * 136 + kk]);
            half8 a1 = *(const half8*)(&As[(mrow + 16) * 136 + kk]);
            #pragma unroll
            for (int nj = 0; nj < 4; nj++) {
                half8 b = *(const half8*)(&Ws[(nj * 16 + (lane & 15)) * 136 + kk]);
                acc[0][nj] = __builtin_amdgcn_mfma_f32_16x16x32_f16(a0, b, acc[0][nj], 0, 0, 0);
                acc[1][nj] = __builtin_amdgcn_mfma_f32_16x16x32_f16(a1, b, acc[1][nj], 0, 0, 0);
            }
        }

        // C/D layout: col = lane&15, row = (lane>>4)*4 + reg; write to panels
        #pragma unroll
        for (int mi = 0; mi < 2; mi++) {
            const int gr0 = row0 + wv * 32 + mi * 16 + (lane >> 4) * 4;
            #pragma unroll
            for (int r = 0; r < 4; r++) {
                const int grow = gr0 + r;
                if (grow < n) {
                    const float s = dinv[grow];
                    #pragma unroll
                    for (int nj = 0; nj < 4; nj++) {
                        const int col = col0 + nj * 16 + (lane & 15);
                        out[(size_t)(col >> 5) * pstride + (size_t)grow * 32 + (col & 31)] =
                            (_Float16)(acc[mi][nj][r] * s);
                    }
                }
            }
        }
    }
}

// ---------------- panel aggregation: fp16 row-sum gather ----------------
// Pass p = blockIdx.y over 32-feature panels (64B rows, L2-resident).
// One node per wave; lanes split into 4 sub-groups -> 4 edges per wave-load.
// out[i, p*32+f] = relu?( (sum_{s in N(i) u {i}} panel_p[s][f]) * dinv[i] + b )
template <bool RELU, bool OUT16>
__global__ __launch_bounds__(256) void aggregate_p(const _Float16* __restrict__ tp,
                                                   size_t pstride,
                                                   const float* __restrict__ dinv,
                                                   const int2* __restrict__ nodeinfo,
                                                   const int* __restrict__ csr_src,
                                                   const float* __restrict__ bias,
                                                   void* __restrict__ outp,
                                                   int F, int n) {
    const int wv = threadIdx.x >> 6;
    const int lane = threadIdx.x & 63;
    const int i = blockIdx.x * 4 + wv;
    if (i >= n) return;
    const int p = blockIdx.y;
    const _Float16* t = tp + (size_t)p * pstride;
    const int sub = lane >> 4;      // which of 4 edges in a quad
    const int sl = lane & 15;       // feature pair [sl*2, sl*2+1]

    const float di = dinv[i];
    const int2 ni = nodeinfo[i];
    const int e0 = ni.x, e1 = ni.x + ni.y;

    float2 a0, a1 = {0.f, 0.f}, a2 = {0.f, 0.f}, a3 = {0.f, 0.f};
    {   // self loop: counted once via sub==0
        float2 v = {0.f, 0.f};
        if (sub == 0) v = __half22float2(*(const __half2*)(t + (size_t)i * 32 + sl * 2));
        a0 = v;
    }

    int e = e0;
    for (; e + 16 <= e1; e += 16) {   // 4 quads = 16 edges in flight
        int sA = csr_src[e + sub];
        int sB = csr_src[e + 4 + sub];
        int sC = csr_src[e + 8 + sub];
        int sD = csr_src[e + 12 + sub];
        float2 vA = __half22float2(*(const __half2*)(t + (size_t)sA * 32 + sl * 2));
        float2 vB = __half22float2(*(const __half2*)(t + (size_t)sB * 32 + sl * 2));
        float2 vC = __half22float2(*(const __half2*)(t + (size_t)sC * 32 + sl * 2));
        float2 vD = __half22float2(*(const __half2*)(t + (size_t)sD * 32 + sl * 2));
        a0.x += vA.x; a0.y += vA.y;
        a1.x += vB.x; a1.y += vB.y;
        a2.x += vC.x; a2.y += vC.y;
        a3.x += vD.x; a3.y += vD.y;
    }
    for (; e < e1; e += 4) {          // predicated tail quads
        bool pr = (e + sub) < e1;
        int s = pr ? csr_src[e + sub] : 0;
        float2 v = {0.f, 0.f};
        if (pr) v = __half22float2(*(const __half2*)(t + (size_t)s * 32 + sl * 2));
        a0.x += v.x; a0.y += v.y;
    }

    float ax = a0.x + a1.x + a2.x + a3.x;
    float ay = a0.y + a1.y + a2.y + a3.y;
    // combine across the 4 sub-groups (lanes sl, sl+16, sl+32, sl+48)
    ax += __shfl_xor(ax, 16); ay += __shfl_xor(ay, 16);
    ax += __shfl_xor(ax, 32); ay += __shfl_xor(ay, 32);

    if (sub == 0) {
        float2 b = ((const float2*)(bias + p * 32))[sl];
        float rx = ax * di + b.x;
        float ry = ay * di + b.y;
        if (RELU) { rx = fmaxf(rx, 0.f); ry = fmaxf(ry, 0.f); }
        if constexpr (OUT16) {
            ((__half2*)((__half*)outp + (size_t)i * F + p * 32))[sl] = __floats2half2_rn(rx, ry);
        } else {
            ((float2*)((float*)outp + (size_t)i * F + p * 32))[sl] = make_float2(rx, ry);
        }
    }
}

// ---------------- fused mean-pool + classifier ----------------
__global__ __launch_bounds__(256) void pool_classify(const float* __restrict__ h2,
                                                     const int* __restrict__ batch, int n,
                                                     const float* __restrict__ Wl,
                                                     const float* __restrict__ bl,
                                                     float* __restrict__ out) {
    __shared__ float partial[4][64];
    __shared__ float pooled_s[64];
    const int g = blockIdx.x;
    const int wv = threadIdx.x >> 6;
    const int lane = threadIdx.x & 63;

    int lo = 0, hi = n;
    while (lo < hi) { int mid = (lo + hi) >> 1; if (batch[mid] < g) lo = mid + 1; else hi = mid; }
    const int start = lo;
    hi = n;
    while (lo < hi) { int mid = (lo + hi) >> 1; if (batch[mid] < g + 1) lo = mid + 1; else hi = mid; }
    const int end = lo;

    float sum = 0.0f;
    int r = start + wv;
    for (; r + 8 <= end; r += 8) {
        float v0 = h2[(size_t)r * 64 + lane];
        float v1 = h2[(size_t)(r + 4) * 64 + lane];
        sum += v0 + v1;
    }
    for (; r < end; r += 4) sum += h2[(size_t)r * 64 + lane];
    partial[wv][lane] = sum;
    __syncthreads();

    if (wv == 0) {
        float s = partial[0][lane] + partial[1][lane] + partial[2][lane] + partial[3][lane];
        float cnt = (float)(end - start);
        pooled_s[lane] = s / fmaxf(cnt, 1.0f);
    }
    __syncthreads();

    if (wv == 0) {
        float acc = bl[lane];
        #pragma unroll 8
        for (int k = 0; k < 64; k++) acc += pooled_s[k] * Wl[k * 64 + lane];
        out[(size_t)g * 64 + lane] = acc;
    }
}

// ---------------- launch ----------------

extern "C" void kernel_launch(void* const* d_in, const int* in_sizes, int n_in,
                              void* d_out, int out_size, void* d_ws, size_t ws_size,
                              hipStream_t stream) {
    const float* x    = (const float*)d_in[0];
    const int*   eidx = (const int*)d_in[1];
    const int*   batch= (const int*)d_in[2];
    const float* W1   = (const float*)d_in[3];
    const float* b1   = (const float*)d_in[4];
    const float* W2   = (const float*)d_in[5];
    const float* b2   = (const float*)d_in[6];
    const float* Wl   = (const float*)d_in[7];
    const float* bl   = (const float*)d_in[8];
    float* out = (float*)d_out;

    const int n_nodes  = in_sizes[0] / FEAT1;     // 50000
    const int n_edges  = in_sizes[1] / 2;         // 800000
    const int n_graphs = out_size / FEAT2;        // 512
    const int* esrc = eidx;
    const int* edst = eidx + n_edges;
    const int nb = (n_nodes + 255) >> 8;          // 196 buckets
    const size_t pstride = (size_t)n_nodes * 32;  // halves per 32-feat panel

    // workspace layout
    char* ws = (char*)d_ws;
    size_t off = 0;
    auto alloc = [&](size_t bytes) -> void* {
        void* p = ws + off;
        off += (bytes + 255) & ~(size_t)255;
        return p;
    };
    _Float16* t1     = (_Float16*)alloc((size_t)n_nodes * FEAT1 * 2); // panel table (reused as t2)
    __half*   h1h    = (__half*)alloc((size_t)n_nodes * FEAT1 * 2);   // fp16 h1 row-major
    float*    h2     = (float*)alloc((size_t)n_nodes * FEAT2 * 4);    // f32 h2 row-major
    float*    dinv   = (float*)alloc((size_t)n_nodes * 4);
    int2*   nodeinfo = (int2*)alloc((size_t)n_nodes * 8);
    int*    bcur     = (int*)alloc((size_t)nb * 4);
    int*    ebin     = (int*)alloc((size_t)nb * BCAP * 4);
    int*    csr      = (int*)alloc((size_t)nb * BCAP * 4);

    const int nrb = (n_nodes + 127) / 128;        // 391 row-tiles
    const int nab = (n_nodes + 3) / 4;            // aggregate blocks (x-dim)

    // 1. bucketed CSR build (also produces nodeinfo + dinv)
    hipMemsetAsync(bcur, 0, (size_t)nb * 4, stream);
    bin_scatter<<<(n_edges + 8191) / 8192, 256, 0, stream>>>(esrc, edst, n_edges, nb, bcur, ebin);
    bucket_csr<<<nb, 256, 0, stream>>>(ebin, bcur, n_nodes, csr, nodeinfo, dinv);

    // 2. layer 1: t1 panels = fp16((x @ W1) * dinv) ; h1 = fp16(relu(agg*di + b1))
    gemm_mfma<FEAT1, false><<<nrb, 256, 0, stream>>>(x, W1, dinv, t1, pstride, n_nodes);
    aggregate_p<true, true><<<dim3(nab, FEAT1 / 32), 256, 0, stream>>>(
        t1, pstride, dinv, nodeinfo, csr, b1, h1h, FEAT1, n_nodes);

    // 3. layer 2: t2 panels = fp16((h1 @ W2) * dinv) ; h2 = agg*di + b2 (f32)
    gemm_mfma<FEAT2, true><<<nrb, 256, 0, stream>>>(h1h, W2, dinv, t1, pstride, n_nodes);
    aggregate_p<false, false><<<dim3(nab, FEAT2 / 32), 256, 0, stream>>>(
        t1, pstride, dinv, nodeinfo, csr, b2, h2, FEAT2, n_nodes);

    // 4. fused mean pool + classifier
    pool_classify<<<n_graphs, 256, 0, stream>>>(h2, batch, n_nodes, Wl, bl, out);
}

// Round 8
// 152.931 us; speedup vs baseline: 1.3950x; 1.3950x over previous
//
#include <hip/hip_runtime.h>
#include <hip/hip_fp16.h>
#include <math.h>

// GCN forward: h1 = relu(norm_agg(x@W1)+b1); h2 = norm_agg(h1@W2)+b2;
// g = mean_pool(h2, batch); out = g@Wl + bl.
// norm_agg = D^-1/2 (A+I) D^-1/2, CSR-by-dst pull.
// R3: GEMM writes t_scaled[i] = (in@W)[i]*dinv[i] as FP16.
// R4: CSR via 2-pass bucketed counting sort (one block owns each csr line).
// R5: pooling as 4-wave blocks with fused classifier.
// R6: GEMMs use MFMA (fp16 LDS staging, mfma_f32_16x16x32_f16).
// R7 REVERTED: panel-split aggregation was issue-bound (VALUBusy 43%, 84us).
// R8: row-major fp16 gather with edge loop unrolled x8 (8 row-gathers in
//     flight per wave; gather is latency-bound per R2 evidence). gemm1 keeps
//     R7's stage-A-once-loop-col-tiles (reads x once).

#define FEAT1 128
#define FEAT2 64
#define BCAP 8192   // edge capacity per bucket; avg load = 4096

using half8 = __attribute__((ext_vector_type(8))) _Float16;
using half4 = __attribute__((ext_vector_type(4))) _Float16;
using f32x4 = __attribute__((ext_vector_type(4))) float;

// ---------------- bucketed CSR build ----------------

// pass 1: scatter edges into per-bucket regions, packed src | ((dst&255)<<18)
// bucket_cursor holds RELATIVE fill counts (memset to 0 before launch).
__global__ __launch_bounds__(256) void bin_scatter(const int* __restrict__ esrc,
                                                   const int* __restrict__ edst,
                                                   int ne, int nb,
                                                   int* __restrict__ bucket_cursor,
                                                   int* __restrict__ ebin) {
    __shared__ int lcnt[256];
    __shared__ int lcur[256];
    const int tid = threadIdx.x;
    const int e0 = blockIdx.x * 8192;
    lcnt[tid] = 0;
    __syncthreads();
    #pragma unroll 4
    for (int k = 0; k < 32; k++) {
        int e = e0 + k * 256 + tid;
        if (e < ne) atomicAdd(&lcnt[edst[e] >> 8], 1);
    }
    __syncthreads();
    if (tid < nb && lcnt[tid] > 0)
        lcur[tid] = atomicAdd(&bucket_cursor[tid], lcnt[tid]);
    __syncthreads();
    #pragma unroll 4
    for (int k = 0; k < 32; k++) {
        int e = e0 + k * 256 + tid;
        if (e < ne) {
            int d = edst[e];
            int b = d >> 8;
            int p = atomicAdd(&lcur[b], 1);          // relative position
            if (p < BCAP)                            // capacity guard
                ebin[b * BCAP + p] = esrc[e] | ((d & 255) << 18); // src < 2^17
        }
    }
}

// pass 2: one block per bucket: LDS counts -> scan -> nodeinfo+dinv -> ticket fill
__global__ __launch_bounds__(256) void bucket_csr(const int* __restrict__ ebin,
                                                  const int* __restrict__ bucket_cursor,
                                                  int n_nodes,
                                                  int* __restrict__ csr,
                                                  int2* __restrict__ nodeinfo,
                                                  float* __restrict__ dinv) {
    __shared__ int lcnt[256];
    __shared__ int lscan[256];
    __shared__ int lcur[256];
    const int b = blockIdx.x;
    const int tid = threadIdx.x;
    const int ebeg = b * BCAP;
    int cnt_b = bucket_cursor[b];
    if (cnt_b > BCAP) cnt_b = BCAP;
    const int eend = ebeg + cnt_b;
    lcnt[tid] = 0;
    __syncthreads();
    for (int e = ebeg + tid; e < eend; e += 256)
        atomicAdd(&lcnt[(ebin[e] >> 18) & 255], 1);
    __syncthreads();
    int v = lcnt[tid];
    lscan[tid] = v;
    __syncthreads();
    for (int off = 1; off < 256; off <<= 1) {
        int u = (tid >= off) ? lscan[tid - off] : 0;
        __syncthreads();
        lscan[tid] += u;
        __syncthreads();
    }
    const int start = ebeg + (lscan[tid] - v);   // exclusive scan position
    const int node = (b << 8) + tid;
    if (node < n_nodes) {
        nodeinfo[node] = make_int2(start, v);
        dinv[node] = (float)(1.0 / sqrt((double)(v + 1)));  // +1 self loop
    }
    lcur[tid] = start;
    __syncthreads();
    for (int e = ebeg + tid; e < eend; e += 256) {
        int pk = ebin[e];
        int p = atomicAdd(&lcur[(pk >> 18) & 255], 1);
        csr[p] = pk & 0x3FFFF;
    }
}

// ---------------- MFMA GEMM with fp16+dinv-scaled output ----------------
// t_out[row, c] = fp16( (A[row,:128] @ W[:128,c]) * dinv[row] )
// Block: 256 thr = 4 waves; 128 rows; A staged ONCE, inner loop over 64-col
// tiles. Padded LDS stride 136 halves -> b128 fragment reads ~2-way (free).
template <int FOUT, bool A_F16>
__global__ __launch_bounds__(256) void gemm_mfma(const void* __restrict__ Aptr,
                                                 const float* __restrict__ W,
                                                 const float* __restrict__ dinv,
                                                 _Float16* __restrict__ out, int n) {
    __shared__ _Float16 As[128 * 136];
    __shared__ _Float16 Ws[64 * 136];
    const int tid = threadIdx.x;
    const int wv = tid >> 6;
    const int lane = tid & 63;
    constexpr int NCT = FOUT / 64;
    const int row0 = blockIdx.x * 128;

    // stage A: 128 rows x 128 k, 2 threads/row (64 cols each)
    {
        const int r = tid >> 1;
        const int c0 = (tid & 1) * 64;
        const int grow = row0 + r;
        if constexpr (A_F16) {
            const _Float16* A = (const _Float16*)Aptr + (size_t)grow * 128 + c0;
            #pragma unroll
            for (int j = 0; j < 8; j++) {
                half8 v = {};
                if (grow < n) v = *(const half8*)(A + j * 8);
                *(half8*)(&As[r * 136 + c0 + j * 8]) = v;
            }
        } else {
            const float* A = (const float*)Aptr + (size_t)grow * 128 + c0;
            #pragma unroll
            for (int j = 0; j < 16; j++) {
                float4 v = {0.f, 0.f, 0.f, 0.f};
                if (grow < n) v = *(const float4*)(A + j * 4);
                half4 hv = {(_Float16)v.x, (_Float16)v.y, (_Float16)v.z, (_Float16)v.w};
                *(half4*)(&As[r * 136 + c0 + j * 4]) = hv;
            }
        }
    }

    for (int ct = 0; ct < NCT; ct++) {
        const int col0 = ct * 64;
        __syncthreads();   // A ready (iter 0) / prior Ws reads done (iter >0)
        // stage W transposed: Ws[col][k], 2 threads/k-row (32 cols each)
        {
            const int k = tid >> 1;
            const int cb = (tid & 1) * 32;
            #pragma unroll
            for (int j = 0; j < 8; j++) {
                int c = cb + j * 4;
                float4 v = *(const float4*)(W + (size_t)k * FOUT + col0 + c);
                Ws[(c + 0) * 136 + k] = (_Float16)v.x;
                Ws[(c + 1) * 136 + k] = (_Float16)v.y;
                Ws[(c + 2) * 136 + k] = (_Float16)v.z;
                Ws[(c + 3) * 136 + k] = (_Float16)v.w;
            }
        }
        __syncthreads();

        f32x4 acc[2][4] = {};
        const int mrow = wv * 32 + (lane & 15);
        const int kb = (lane >> 4) * 8;
        #pragma unroll
        for (int ks = 0; ks < 4; ks++) {
            const int kk = ks * 32 + kb;
            half8 a0 = *(const half8*)(&As[mrow * 136 + kk]);
            half8 a1 = *(const half8*)(&As[(mrow + 16) * 136 + kk]);
            #pragma unroll
            for (int nj = 0; nj < 4; nj++) {
                half8 b = *(const half8*)(&Ws[(nj * 16 + (lane & 15)) * 136 + kk]);
                acc[0][nj] = __builtin_amdgcn_mfma_f32_16x16x32_f16(a0, b, acc[0][nj], 0, 0, 0);
                acc[1][nj] = __builtin_amdgcn_mfma_f32_16x16x32_f16(a1, b, acc[1][nj], 0, 0, 0);
            }
        }

        // C/D layout: col = lane&15, row = (lane>>4)*4 + reg
        #pragma unroll
        for (int mi = 0; mi < 2; mi++) {
            const int gr0 = row0 + wv * 32 + mi * 16 + (lane >> 4) * 4;
            #pragma unroll
            for (int r = 0; r < 4; r++) {
                const int grow = gr0 + r;
                if (grow < n) {
                    const float s = dinv[grow];
                    #pragma unroll
                    for (int nj = 0; nj < 4; nj++) {
                        out[(size_t)grow * FOUT + col0 + nj * 16 + (lane & 15)] =
                            (_Float16)(acc[mi][nj][r] * s);
                    }
                }
            }
        }
    }
}

// ---------------- normalized aggregation: fp16 row-sum gather, 8-deep ----------------
// out[i] = relu?( (sum_{s in N(i) u {i}} t_scaled[s]) * dinv[i] + b )
// One node per wave; 8 independent row-gathers in flight per wave.
template <int F, bool RELU, bool OUT16>
__global__ __launch_bounds__(256) void aggregate_h(const __half* __restrict__ t,
                                                   const float* __restrict__ dinv,
                                                   const int2* __restrict__ nodeinfo,
                                                   const int* __restrict__ csr_src,
                                                   const float* __restrict__ bias,
                                                   void* __restrict__ outp, int n) {
    const int wv = threadIdx.x >> 6;
    const int lane = threadIdx.x & 63;
    const int i = blockIdx.x * 4 + wv;
    if (i >= n) return;
    const float di = dinv[i];
    const int2 ni = nodeinfo[i];
    const int e0 = ni.x, e1 = ni.x + ni.y;

    if constexpr (F == 128) {
        float2 a0, a1 = {0.f, 0.f}, a2 = {0.f, 0.f}, a3 = {0.f, 0.f};
        a0 = __half22float2(((const __half2*)(t + (size_t)i * F))[lane]);  // self
        int e = e0;
        for (; e + 8 <= e1; e += 8) {     // 8 row-gathers in flight
            int s0 = csr_src[e + 0], s1 = csr_src[e + 1], s2 = csr_src[e + 2], s3 = csr_src[e + 3];
            int s4 = csr_src[e + 4], s5 = csr_src[e + 5], s6 = csr_src[e + 6], s7 = csr_src[e + 7];
            float2 v0 = __half22float2(((const __half2*)(t + (size_t)s0 * F))[lane]);
            float2 v1 = __half22float2(((const __half2*)(t + (size_t)s1 * F))[lane]);
            float2 v2 = __half22float2(((const __half2*)(t + (size_t)s2 * F))[lane]);
            float2 v3 = __half22float2(((const __half2*)(t + (size_t)s3 * F))[lane]);
            float2 v4 = __half22float2(((const __half2*)(t + (size_t)s4 * F))[lane]);
            float2 v5 = __half22float2(((const __half2*)(t + (size_t)s5 * F))[lane]);
            float2 v6 = __half22float2(((const __half2*)(t + (size_t)s6 * F))[lane]);
            float2 v7 = __half22float2(((const __half2*)(t + (size_t)s7 * F))[lane]);
            a0.x += v0.x + v4.x; a0.y += v0.y + v4.y;
            a1.x += v1.x + v5.x; a1.y += v1.y + v5.y;
            a2.x += v2.x + v6.x; a2.y += v2.y + v6.y;
            a3.x += v3.x + v7.x; a3.y += v3.y + v7.y;
        }
        for (; e + 4 <= e1; e += 4) {
            int s0 = csr_src[e + 0], s1 = csr_src[e + 1], s2 = csr_src[e + 2], s3 = csr_src[e + 3];
            float2 v0 = __half22float2(((const __half2*)(t + (size_t)s0 * F))[lane]);
            float2 v1 = __half22float2(((const __half2*)(t + (size_t)s1 * F))[lane]);
            float2 v2 = __half22float2(((const __half2*)(t + (size_t)s2 * F))[lane]);
            float2 v3 = __half22float2(((const __half2*)(t + (size_t)s3 * F))[lane]);
            a0.x += v0.x; a0.y += v0.y;
            a1.x += v1.x; a1.y += v1.y;
            a2.x += v2.x; a2.y += v2.y;
            a3.x += v3.x; a3.y += v3.y;
        }
        for (; e < e1; e++) {
            int s = csr_src[e];
            float2 v = __half22float2(((const __half2*)(t + (size_t)s * F))[lane]);
            a0.x += v.x; a0.y += v.y;
        }
        float2 b = ((const float2*)bias)[lane];
        float rx = (a0.x + a1.x + a2.x + a3.x) * di + b.x;
        float ry = (a0.y + a1.y + a2.y + a3.y) * di + b.y;
        if (RELU) { rx = fmaxf(rx, 0.f); ry = fmaxf(ry, 0.f); }
        if constexpr (OUT16) {
            ((__half2*)((__half*)outp + (size_t)i * F))[lane] = __floats2half2_rn(rx, ry);
        } else {
            ((float2*)((float*)outp + (size_t)i * F))[lane] = make_float2(rx, ry);
        }
    } else {
        float a0, a1 = 0.f, a2 = 0.f, a3 = 0.f;
        a0 = __half2float(t[(size_t)i * F + lane]);  // self
        int e = e0;
        for (; e + 8 <= e1; e += 8) {     // 8 row-gathers in flight
            int s0 = csr_src[e + 0], s1 = csr_src[e + 1], s2 = csr_src[e + 2], s3 = csr_src[e + 3];
            int s4 = csr_src[e + 4], s5 = csr_src[e + 5], s6 = csr_src[e + 6], s7 = csr_src[e + 7];
            float v0 = __half2float(t[(size_t)s0 * F + lane]);
            float v1 = __half2float(t[(size_t)s1 * F + lane]);
            float v2 = __half2float(t[(size_t)s2 * F + lane]);
            float v3 = __half2float(t[(size_t)s3 * F + lane]);
            float v4 = __half2float(t[(size_t)s4 * F + lane]);
            float v5 = __half2float(t[(size_t)s5 * F + lane]);
            float v6 = __half2float(t[(size_t)s6 * F + lane]);
            float v7 = __half2float(t[(size_t)s7 * F + lane]);
            a0 += v0 + v4; a1 += v1 + v5; a2 += v2 + v6; a3 += v3 + v7;
        }
        for (; e + 4 <= e1; e += 4) {
            int s0 = csr_src[e + 0], s1 = csr_src[e + 1], s2 = csr_src[e + 2], s3 = csr_src[e + 3];
            a0 += __half2float(t[(size_t)s0 * F + lane]);
            a1 += __half2float(t[(size_t)s1 * F + lane]);
            a2 += __half2float(t[(size_t)s2 * F + lane]);
            a3 += __half2float(t[(size_t)s3 * F + lane]);
        }
        for (; e < e1; e++) {
            a0 += __half2float(t[(size_t)csr_src[e] * F + lane]);
        }
        float r = (a0 + a1 + a2 + a3) * di + bias[lane];
        if (RELU) r = fmaxf(r, 0.f);
        if constexpr (OUT16) {
            ((__half*)outp)[(size_t)i * F + lane] = __float2half(r);
        } else {
            ((float*)outp)[(size_t)i * F + lane] = r;
        }
    }
}

// ---------------- fused mean-pool + classifier ----------------
__global__ __launch_bounds__(256) void pool_classify(const float* __restrict__ h2,
                                                     const int* __restrict__ batch, int n,
                                                     const float* __restrict__ Wl,
                                                     const float* __restrict__ bl,
                                                     float* __restrict__ out) {
    __shared__ float partial[4][64];
    __shared__ float pooled_s[64];
    const int g = blockIdx.x;
    const int wv = threadIdx.x >> 6;
    const int lane = threadIdx.x & 63;

    int lo = 0, hi = n;
    while (lo < hi) { int mid = (lo + hi) >> 1; if (batch[mid] < g) lo = mid + 1; else hi = mid; }
    const int start = lo;
    hi = n;
    while (lo < hi) { int mid = (lo + hi) >> 1; if (batch[mid] < g + 1) lo = mid + 1; else hi = mid; }
    const int end = lo;

    float sum = 0.0f;
    int r = start + wv;
    for (; r + 8 <= end; r += 8) {
        float v0 = h2[(size_t)r * 64 + lane];
        float v1 = h2[(size_t)(r + 4) * 64 + lane];
        sum += v0 + v1;
    }
    for (; r < end; r += 4) sum += h2[(size_t)r * 64 + lane];
    partial[wv][lane] = sum;
    __syncthreads();

    if (wv == 0) {
        float s = partial[0][lane] + partial[1][lane] + partial[2][lane] + partial[3][lane];
        float cnt = (float)(end - start);
        pooled_s[lane] = s / fmaxf(cnt, 1.0f);
    }
    __syncthreads();

    if (wv == 0) {
        float acc = bl[lane];
        #pragma unroll 8
        for (int k = 0; k < 64; k++) acc += pooled_s[k] * Wl[k * 64 + lane];
        out[(size_t)g * 64 + lane] = acc;
    }
}

// ---------------- launch ----------------

extern "C" void kernel_launch(void* const* d_in, const int* in_sizes, int n_in,
                              void* d_out, int out_size, void* d_ws, size_t ws_size,
                              hipStream_t stream) {
    const float* x    = (const float*)d_in[0];
    const int*   eidx = (const int*)d_in[1];
    const int*   batch= (const int*)d_in[2];
    const float* W1   = (const float*)d_in[3];
    const float* b1   = (const float*)d_in[4];
    const float* W2   = (const float*)d_in[5];
    const float* b2   = (const float*)d_in[6];
    const float* Wl   = (const float*)d_in[7];
    const float* bl   = (const float*)d_in[8];
    float* out = (float*)d_out;

    const int n_nodes  = in_sizes[0] / FEAT1;     // 50000
    const int n_edges  = in_sizes[1] / 2;         // 800000
    const int n_graphs = out_size / FEAT2;        // 512
    const int* esrc = eidx;
    const int* edst = eidx + n_edges;
    const int nb = (n_nodes + 255) >> 8;          // 196 buckets

    // workspace layout
    char* ws = (char*)d_ws;
    size_t off = 0;
    auto alloc = [&](size_t bytes) -> void* {
        void* p = ws + off;
        off += (bytes + 255) & ~(size_t)255;
        return p;
    };
    _Float16* t1     = (_Float16*)alloc((size_t)n_nodes * FEAT1 * 2); // fp16 scaled table (reused as t2)
    __half*   h1h    = (__half*)alloc((size_t)n_nodes * FEAT1 * 2);   // fp16 h1 (agg1 out, gemm2 in)
    float*    h2     = (float*)alloc((size_t)n_nodes * FEAT2 * 4);    // f32 h2 (agg2 out, pool in)
    float*    dinv   = (float*)alloc((size_t)n_nodes * 4);
    int2*   nodeinfo = (int2*)alloc((size_t)n_nodes * 8);
    int*    bcur     = (int*)alloc((size_t)nb * 4);
    int*    ebin     = (int*)alloc((size_t)nb * BCAP * 4);
    int*    csr      = (int*)alloc((size_t)nb * BCAP * 4);

    const int nrb = (n_nodes + 127) / 128;        // 391 row-tiles

    // 1. bucketed CSR build (also produces nodeinfo + dinv)
    hipMemsetAsync(bcur, 0, (size_t)nb * 4, stream);
    bin_scatter<<<(n_edges + 8191) / 8192, 256, 0, stream>>>(esrc, edst, n_edges, nb, bcur, ebin);
    bucket_csr<<<nb, 256, 0, stream>>>(ebin, bcur, n_nodes, csr, nodeinfo, dinv);

    // 2. layer 1: t1 = fp16((x @ W1) * dinv) ; h1 = fp16(relu(agg(t1)*dinv + b1))
    gemm_mfma<FEAT1, false><<<nrb, 256, 0, stream>>>(x, W1, dinv, t1, n_nodes);
    aggregate_h<FEAT1, true, true><<<(n_nodes + 3) / 4, 256, 0, stream>>>(
        (const __half*)t1, dinv, nodeinfo, csr, b1, h1h, n_nodes);

    // 3. layer 2: t2 = fp16((h1 @ W2) * dinv) ; h2 = agg(t2)*dinv + b2 (f32)
    gemm_mfma<FEAT2, true><<<nrb, 256, 0, stream>>>(h1h, W2, dinv, t1, n_nodes);
    aggregate_h<FEAT2, false, false><<<(n_nodes + 3) / 4, 256, 0, stream>>>(
        (const __half*)t1, dinv, nodeinfo, csr, b2, h2, n_nodes);

    // 4. fused mean pool + classifier
    pool_classify<<<n_graphs, 256, 0, stream>>>(h2, batch, n_nodes, Wl, bl, out);
}

// Round 9
// 151.805 us; speedup vs baseline: 1.4054x; 1.0074x over previous
//
#include <hip/hip_runtime.h>
#include <hip/hip_fp16.h>
#include <math.h>

// GCN forward: h1 = relu(norm_agg(x@W1)+b1); h2 = norm_agg(h1@W2)+b2;
// g = mean_pool(h2, batch); out = g@Wl + bl.
// norm_agg = D^-1/2 (A+I) D^-1/2, CSR-by-dst pull.
// R3: GEMM writes t_scaled[i] = (in@W)[i]*dinv[i] as FP16.
// R4: CSR via 2-pass bucketed counting sort (one block owns each csr line).
// R6: GEMMs use MFMA (fp16 LDS staging, mfma_f32_16x16x32_f16).
// R8: row-major fp16 gather, edge loop unrolled x8 (latency-bound gather).
// R9: agg2 accumulates pooled sums directly via global f32 atomics (h2 buffer
//     and pool kernel eliminated); tiny classify kernel does /cnt + b2 + @Wl;
//     bin_scatter caches edst in regs (reads edges 1.5x not 2x); one merged
//     memset for bcur+pooled.

#define FEAT1 128
#define FEAT2 64
#define BCAP 8192   // edge capacity per bucket; avg load = 4096

using half8 = __attribute__((ext_vector_type(8))) _Float16;
using half4 = __attribute__((ext_vector_type(4))) _Float16;
using f32x4 = __attribute__((ext_vector_type(4))) float;

// ---------------- bucketed CSR build ----------------

// pass 1: scatter edges into per-bucket regions, packed src | ((dst&255)<<18)
// bucket_cursor holds RELATIVE fill counts (memset to 0 before launch).
__global__ __launch_bounds__(256) void bin_scatter(const int* __restrict__ esrc,
                                                   const int* __restrict__ edst,
                                                   int ne, int nb,
                                                   int* __restrict__ bucket_cursor,
                                                   int* __restrict__ ebin) {
    __shared__ int lcnt[256];
    __shared__ int lcur[256];
    const int tid = threadIdx.x;
    const int e0 = blockIdx.x * 8192;
    int dcache[32];                     // edst cached in regs across phases
    lcnt[tid] = 0;
    __syncthreads();
    #pragma unroll
    for (int k = 0; k < 32; k++) {
        int e = e0 + k * 256 + tid;
        dcache[k] = (e < ne) ? edst[e] : -1;
        if (dcache[k] >= 0) atomicAdd(&lcnt[dcache[k] >> 8], 1);
    }
    __syncthreads();
    if (tid < nb && lcnt[tid] > 0)
        lcur[tid] = atomicAdd(&bucket_cursor[tid], lcnt[tid]);
    __syncthreads();
    #pragma unroll
    for (int k = 0; k < 32; k++) {
        int d = dcache[k];
        if (d >= 0) {
            int e = e0 + k * 256 + tid;
            int b = d >> 8;
            int p = atomicAdd(&lcur[b], 1);          // relative position
            if (p < BCAP)                            // capacity guard
                ebin[b * BCAP + p] = esrc[e] | ((d & 255) << 18); // src < 2^17
        }
    }
}

// pass 2: one block per bucket: LDS counts -> scan -> nodeinfo+dinv -> ticket fill
__global__ __launch_bounds__(256) void bucket_csr(const int* __restrict__ ebin,
                                                  const int* __restrict__ bucket_cursor,
                                                  int n_nodes,
                                                  int* __restrict__ csr,
                                                  int2* __restrict__ nodeinfo,
                                                  float* __restrict__ dinv) {
    __shared__ int lcnt[256];
    __shared__ int lscan[256];
    __shared__ int lcur[256];
    const int b = blockIdx.x;
    const int tid = threadIdx.x;
    const int ebeg = b * BCAP;
    int cnt_b = bucket_cursor[b];
    if (cnt_b > BCAP) cnt_b = BCAP;
    const int eend = ebeg + cnt_b;
    lcnt[tid] = 0;
    __syncthreads();
    for (int e = ebeg + tid; e < eend; e += 256)
        atomicAdd(&lcnt[(ebin[e] >> 18) & 255], 1);
    __syncthreads();
    int v = lcnt[tid];
    lscan[tid] = v;
    __syncthreads();
    for (int off = 1; off < 256; off <<= 1) {
        int u = (tid >= off) ? lscan[tid - off] : 0;
        __syncthreads();
        lscan[tid] += u;
        __syncthreads();
    }
    const int start = ebeg + (lscan[tid] - v);   // exclusive scan position
    const int node = (b << 8) + tid;
    if (node < n_nodes) {
        nodeinfo[node] = make_int2(start, v);
        dinv[node] = (float)(1.0 / sqrt((double)(v + 1)));  // +1 self loop
    }
    lcur[tid] = start;
    __syncthreads();
    for (int e = ebeg + tid; e < eend; e += 256) {
        int pk = ebin[e];
        int p = atomicAdd(&lcur[(pk >> 18) & 255], 1);
        csr[p] = pk & 0x3FFFF;
    }
}

// ---------------- MFMA GEMM with fp16+dinv-scaled output ----------------
// t_out[row, c] = fp16( (A[row,:128] @ W[:128,c]) * dinv[row] )
// Block: 256 thr = 4 waves; 128 rows; A staged ONCE, inner loop over 64-col
// tiles. Padded LDS stride 136 halves -> b128 fragment reads ~2-way (free).
template <int FOUT, bool A_F16>
__global__ __launch_bounds__(256) void gemm_mfma(const void* __restrict__ Aptr,
                                                 const float* __restrict__ W,
                                                 const float* __restrict__ dinv,
                                                 _Float16* __restrict__ out, int n) {
    __shared__ _Float16 As[128 * 136];
    __shared__ _Float16 Ws[64 * 136];
    const int tid = threadIdx.x;
    const int wv = tid >> 6;
    const int lane = tid & 63;
    constexpr int NCT = FOUT / 64;
    const int row0 = blockIdx.x * 128;

    // stage A: 128 rows x 128 k, 2 threads/row (64 cols each)
    {
        const int r = tid >> 1;
        const int c0 = (tid & 1) * 64;
        const int grow = row0 + r;
        if constexpr (A_F16) {
            const _Float16* A = (const _Float16*)Aptr + (size_t)grow * 128 + c0;
            #pragma unroll
            for (int j = 0; j < 8; j++) {
                half8 v = {};
                if (grow < n) v = *(const half8*)(A + j * 8);
                *(half8*)(&As[r * 136 + c0 + j * 8]) = v;
            }
        } else {
            const float* A = (const float*)Aptr + (size_t)grow * 128 + c0;
            #pragma unroll
            for (int j = 0; j < 16; j++) {
                float4 v = {0.f, 0.f, 0.f, 0.f};
                if (grow < n) v = *(const float4*)(A + j * 4);
                half4 hv = {(_Float16)v.x, (_Float16)v.y, (_Float16)v.z, (_Float16)v.w};
                *(half4*)(&As[r * 136 + c0 + j * 4]) = hv;
            }
        }
    }

    for (int ct = 0; ct < NCT; ct++) {
        const int col0 = ct * 64;
        __syncthreads();   // A ready (iter 0) / prior Ws reads done (iter >0)
        // stage W transposed: Ws[col][k], 2 threads/k-row (32 cols each)
        {
            const int k = tid >> 1;
            const int cb = (tid & 1) * 32;
            #pragma unroll
            for (int j = 0; j < 8; j++) {
                int c = cb + j * 4;
                float4 v = *(const float4*)(W + (size_t)k * FOUT + col0 + c);
                Ws[(c + 0) * 136 + k] = (_Float16)v.x;
                Ws[(c + 1) * 136 + k] = (_Float16)v.y;
                Ws[(c + 2) * 136 + k] = (_Float16)v.z;
                Ws[(c + 3) * 136 + k] = (_Float16)v.w;
            }
        }
        __syncthreads();

        f32x4 acc[2][4] = {};
        const int mrow = wv * 32 + (lane & 15);
        const int kb = (lane >> 4) * 8;
        #pragma unroll
        for (int ks = 0; ks < 4; ks++) {
            const int kk = ks * 32 + kb;
            half8 a0 = *(const half8*)(&As[mrow * 136 + kk]);
            half8 a1 = *(const half8*)(&As[(mrow + 16) * 136 + kk]);
            #pragma unroll
            for (int nj = 0; nj < 4; nj++) {
                half8 b = *(const half8*)(&Ws[(nj * 16 + (lane & 15)) * 136 + kk]);
                acc[0][nj] = __builtin_amdgcn_mfma_f32_16x16x32_f16(a0, b, acc[0][nj], 0, 0, 0);
                acc[1][nj] = __builtin_amdgcn_mfma_f32_16x16x32_f16(a1, b, acc[1][nj], 0, 0, 0);
            }
        }

        // C/D layout: col = lane&15, row = (lane>>4)*4 + reg
        #pragma unroll
        for (int mi = 0; mi < 2; mi++) {
            const int gr0 = row0 + wv * 32 + mi * 16 + (lane >> 4) * 4;
            #pragma unroll
            for (int r = 0; r < 4; r++) {
                const int grow = gr0 + r;
                if (grow < n) {
                    const float s = dinv[grow];
                    #pragma unroll
                    for (int nj = 0; nj < 4; nj++) {
                        out[(size_t)grow * FOUT + col0 + nj * 16 + (lane & 15)] =
                            (_Float16)(acc[mi][nj][r] * s);
                    }
                }
            }
        }
    }
}

// ---------------- layer-1 aggregation: fp16 row-sum gather, 8-deep ----------------
// h1[i] = fp16( relu( (sum_{s in N(i) u {i}} t1[s]) * dinv[i] + b1 ) )
__global__ __launch_bounds__(256) void aggregate_l1(const __half* __restrict__ t,
                                                    const float* __restrict__ dinv,
                                                    const int2* __restrict__ nodeinfo,
                                                    const int* __restrict__ csr_src,
                                                    const float* __restrict__ bias,
                                                    __half* __restrict__ outp, int n) {
    constexpr int F = 128;
    const int wv = threadIdx.x >> 6;
    const int lane = threadIdx.x & 63;
    const int i = blockIdx.x * 4 + wv;
    if (i >= n) return;
    const float di = dinv[i];
    const int2 ni = nodeinfo[i];
    const int e0 = ni.x, e1 = ni.x + ni.y;

    float2 a0, a1 = {0.f, 0.f}, a2 = {0.f, 0.f}, a3 = {0.f, 0.f};
    a0 = __half22float2(((const __half2*)(t + (size_t)i * F))[lane]);  // self
    int e = e0;
    for (; e + 8 <= e1; e += 8) {     // 8 row-gathers in flight
        int s0 = csr_src[e + 0], s1 = csr_src[e + 1], s2 = csr_src[e + 2], s3 = csr_src[e + 3];
        int s4 = csr_src[e + 4], s5 = csr_src[e + 5], s6 = csr_src[e + 6], s7 = csr_src[e + 7];
        float2 v0 = __half22float2(((const __half2*)(t + (size_t)s0 * F))[lane]);
        float2 v1 = __half22float2(((const __half2*)(t + (size_t)s1 * F))[lane]);
        float2 v2 = __half22float2(((const __half2*)(t + (size_t)s2 * F))[lane]);
        float2 v3 = __half22float2(((const __half2*)(t + (size_t)s3 * F))[lane]);
        float2 v4 = __half22float2(((const __half2*)(t + (size_t)s4 * F))[lane]);
        float2 v5 = __half22float2(((const __half2*)(t + (size_t)s5 * F))[lane]);
        float2 v6 = __half22float2(((const __half2*)(t + (size_t)s6 * F))[lane]);
        float2 v7 = __half22float2(((const __half2*)(t + (size_t)s7 * F))[lane]);
        a0.x += v0.x + v4.x; a0.y += v0.y + v4.y;
        a1.x += v1.x + v5.x; a1.y += v1.y + v5.y;
        a2.x += v2.x + v6.x; a2.y += v2.y + v6.y;
        a3.x += v3.x + v7.x; a3.y += v3.y + v7.y;
    }
    for (; e + 4 <= e1; e += 4) {
        int s0 = csr_src[e + 0], s1 = csr_src[e + 1], s2 = csr_src[e + 2], s3 = csr_src[e + 3];
        float2 v0 = __half22float2(((const __half2*)(t + (size_t)s0 * F))[lane]);
        float2 v1 = __half22float2(((const __half2*)(t + (size_t)s1 * F))[lane]);
        float2 v2 = __half22float2(((const __half2*)(t + (size_t)s2 * F))[lane]);
        float2 v3 = __half22float2(((const __half2*)(t + (size_t)s3 * F))[lane]);
        a0.x += v0.x; a0.y += v0.y;
        a1.x += v1.x; a1.y += v1.y;
        a2.x += v2.x; a2.y += v2.y;
        a3.x += v3.x; a3.y += v3.y;
    }
    for (; e < e1; e++) {
        int s = csr_src[e];
        float2 v = __half22float2(((const __half2*)(t + (size_t)s * F))[lane]);
        a0.x += v.x; a0.y += v.y;
    }
    float2 b = ((const float2*)bias)[lane];
    float rx = (a0.x + a1.x + a2.x + a3.x) * di + b.x;
    float ry = (a0.y + a1.y + a2.y + a3.y) * di + b.y;
    rx = fmaxf(rx, 0.f); ry = fmaxf(ry, 0.f);
    ((__half2*)(outp + (size_t)i * F))[lane] = __floats2half2_rn(rx, ry);
}

// ---------------- layer-2 aggregation fused with pooled accumulation ----------------
// pooled_sums[batch[i]][f] += (sum_{s in N(i) u {i}} t2[s][f]) * dinv[i]
// (bias b2 and /cnt applied in classify). F=64: 1 half/lane, 8-deep gather.
__global__ __launch_bounds__(256) void aggregate_pool(const __half* __restrict__ t,
                                                      const float* __restrict__ dinv,
                                                      const int2* __restrict__ nodeinfo,
                                                      const int* __restrict__ csr_src,
                                                      const int* __restrict__ batch,
                                                      float* __restrict__ pooled_sums, int n) {
    constexpr int F = 64;
    const int wv = threadIdx.x >> 6;
    const int lane = threadIdx.x & 63;
    const int i = blockIdx.x * 4 + wv;
    if (i >= n) return;
    const float di = dinv[i];
    const int2 ni = nodeinfo[i];
    const int e0 = ni.x, e1 = ni.x + ni.y;

    float a0, a1 = 0.f, a2 = 0.f, a3 = 0.f;
    a0 = __half2float(t[(size_t)i * F + lane]);  // self
    int e = e0;
    for (; e + 8 <= e1; e += 8) {     // 8 row-gathers in flight
        int s0 = csr_src[e + 0], s1 = csr_src[e + 1], s2 = csr_src[e + 2], s3 = csr_src[e + 3];
        int s4 = csr_src[e + 4], s5 = csr_src[e + 5], s6 = csr_src[e + 6], s7 = csr_src[e + 7];
        float v0 = __half2float(t[(size_t)s0 * F + lane]);
        float v1 = __half2float(t[(size_t)s1 * F + lane]);
        float v2 = __half2float(t[(size_t)s2 * F + lane]);
        float v3 = __half2float(t[(size_t)s3 * F + lane]);
        float v4 = __half2float(t[(size_t)s4 * F + lane]);
        float v5 = __half2float(t[(size_t)s5 * F + lane]);
        float v6 = __half2float(t[(size_t)s6 * F + lane]);
        float v7 = __half2float(t[(size_t)s7 * F + lane]);
        a0 += v0 + v4; a1 += v1 + v5; a2 += v2 + v6; a3 += v3 + v7;
    }
    for (; e + 4 <= e1; e += 4) {
        int s0 = csr_src[e + 0], s1 = csr_src[e + 1], s2 = csr_src[e + 2], s3 = csr_src[e + 3];
        a0 += __half2float(t[(size_t)s0 * F + lane]);
        a1 += __half2float(t[(size_t)s1 * F + lane]);
        a2 += __half2float(t[(size_t)s2 * F + lane]);
        a3 += __half2float(t[(size_t)s3 * F + lane]);
    }
    for (; e < e1; e++) {
        a0 += __half2float(t[(size_t)csr_src[e] * F + lane]);
    }
    float r = (a0 + a1 + a2 + a3) * di;
    const int g = batch[i];
    atomicAdd(&pooled_sums[(size_t)g * F + lane], r);
}

// ---------------- classifier: /cnt + b2, then @Wl + bl ----------------
__global__ __launch_bounds__(64) void classify(const float* __restrict__ pooled_sums,
                                               const int* __restrict__ batch, int n,
                                               const float* __restrict__ b2,
                                               const float* __restrict__ Wl,
                                               const float* __restrict__ bl,
                                               float* __restrict__ out) {
    __shared__ float pr[64];
    const int g = blockIdx.x;
    const int lane = threadIdx.x;
    // count nodes in graph g (sorted batch)
    int lo = 0, hi = n;
    while (lo < hi) { int mid = (lo + hi) >> 1; if (batch[mid] < g) lo = mid + 1; else hi = mid; }
    const int start = lo;
    hi = n;
    while (lo < hi) { int mid = (lo + hi) >> 1; if (batch[mid] < g + 1) lo = mid + 1; else hi = mid; }
    const float cnt = (float)(lo - start);
    float p = pooled_sums[(size_t)g * 64 + lane] / fmaxf(cnt, 1.0f) + b2[lane];
    pr[lane] = p;
    __syncthreads();
    float acc = bl[lane];
    #pragma unroll 8
    for (int k = 0; k < 64; k++) acc += pr[k] * Wl[k * 64 + lane];
    out[(size_t)g * 64 + lane] = acc;
}

// ---------------- launch ----------------

extern "C" void kernel_launch(void* const* d_in, const int* in_sizes, int n_in,
                              void* d_out, int out_size, void* d_ws, size_t ws_size,
                              hipStream_t stream) {
    const float* x    = (const float*)d_in[0];
    const int*   eidx = (const int*)d_in[1];
    const int*   batch= (const int*)d_in[2];
    const float* W1   = (const float*)d_in[3];
    const float* b1   = (const float*)d_in[4];
    const float* W2   = (const float*)d_in[5];
    const float* b2   = (const float*)d_in[6];
    const float* Wl   = (const float*)d_in[7];
    const float* bl   = (const float*)d_in[8];
    float* out = (float*)d_out;

    const int n_nodes  = in_sizes[0] / FEAT1;     // 50000
    const int n_edges  = in_sizes[1] / 2;         // 800000
    const int n_graphs = out_size / FEAT2;        // 512
    const int* esrc = eidx;
    const int* edst = eidx + n_edges;
    const int nb = (n_nodes + 255) >> 8;          // 196 buckets

    // workspace layout
    char* ws = (char*)d_ws;
    size_t off = 0;
    auto alloc = [&](size_t bytes) -> void* {
        void* p = ws + off;
        off += (bytes + 255) & ~(size_t)255;
        return p;
    };
    _Float16* t1     = (_Float16*)alloc((size_t)n_nodes * FEAT1 * 2); // fp16 scaled table (reused as t2)
    __half*   h1h    = (__half*)alloc((size_t)n_nodes * FEAT1 * 2);   // fp16 h1 (agg1 out, gemm2 in)
    float*    dinv   = (float*)alloc((size_t)n_nodes * 4);
    int2*   nodeinfo = (int2*)alloc((size_t)n_nodes * 8);
    int*    bcur     = (int*)alloc((size_t)nb * 4);                   // zeroed (merged memset)
    float*  pooled   = (float*)alloc((size_t)n_graphs * FEAT2 * 4);   // zeroed (merged memset)
    char*   zend     = (char*)alloc(0);                               // end of zeroed region
    int*    ebin     = (int*)alloc((size_t)nb * BCAP * 4);
    int*    csr      = (int*)alloc((size_t)nb * BCAP * 4);

    const int nrb = (n_nodes + 127) / 128;        // 391 row-tiles

    // 1. zero bcur + pooled in one memset; bucketed CSR build
    hipMemsetAsync(bcur, 0, (size_t)(zend - (char*)bcur), stream);
    bin_scatter<<<(n_edges + 8191) / 8192, 256, 0, stream>>>(esrc, edst, n_edges, nb, bcur, ebin);
    bucket_csr<<<nb, 256, 0, stream>>>(ebin, bcur, n_nodes, csr, nodeinfo, dinv);

    // 2. layer 1: t1 = fp16((x @ W1) * dinv) ; h1 = fp16(relu(agg(t1)*dinv + b1))
    gemm_mfma<FEAT1, false><<<nrb, 256, 0, stream>>>(x, W1, dinv, t1, n_nodes);
    aggregate_l1<<<(n_nodes + 3) / 4, 256, 0, stream>>>(
        (const __half*)t1, dinv, nodeinfo, csr, b1, h1h, n_nodes);

    // 3. layer 2: t2 = fp16((h1 @ W2) * dinv) ; pooled_sums += agg(t2)*dinv per graph
    gemm_mfma<FEAT2, true><<<nrb, 256, 0, stream>>>(h1h, W2, dinv, t1, n_nodes);
    aggregate_pool<<<(n_nodes + 3) / 4, 256, 0, stream>>>(
        (const __half*)t1, dinv, nodeinfo, csr, batch, pooled, n_nodes);

    // 4. classifier: /cnt + b2, @Wl + bl
    classify<<<n_graphs, 64, 0, stream>>>(pooled, batch, n_nodes, b2, Wl, bl, out);
}

// Round 10
// 151.501 us; speedup vs baseline: 1.4082x; 1.0020x over previous
//
#include <hip/hip_runtime.h>
#include <hip/hip_fp16.h>
#include <math.h>

// GCN forward: h1 = relu(norm_agg(x@W1)+b1); h2 = norm_agg(h1@W2)+b2;
// g = mean_pool(h2, batch); out = g@Wl + bl.
// norm_agg = D^-1/2 (A+I) D^-1/2, CSR-by-dst pull.
// R3: GEMM writes t_scaled[i] = (in@W)[i]*dinv[i] as FP16.
// R4: CSR via 2-pass bucketed counting sort (one block owns each csr line).
// R8: row-major fp16 gather, edge loop unrolled x8 (latency-bound gather).
// R9: agg2 accumulates pooled sums via global f32 atomics; classify kernel.
// R10: LDS-free MFMA GEMM — A/B fragments loaded DIRECTLY from global
//      (fragment = 8 contiguous k-elems/lane). W pre-transposed to fp16
//      Wt[col][k] by the prep kernel (also zeros bcur+pooled). No barriers,
//      no LDS -> VGPR-bound occupancy, no staging prologue.

#define FEAT1 128
#define FEAT2 64
#define BCAP 8192   // edge capacity per bucket; avg load = 4096

using half8 = __attribute__((ext_vector_type(8))) _Float16;
using f32x4 = __attribute__((ext_vector_type(4))) float;

// ---------------- prep: zero bcur+pooled, transpose W1/W2 to fp16 ----------------
__global__ __launch_bounds__(256) void prep(const float* __restrict__ W1,
                                            const float* __restrict__ W2,
                                            _Float16* __restrict__ Wt1,
                                            _Float16* __restrict__ Wt2,
                                            int* __restrict__ bcur,
                                            float* __restrict__ pooled,
                                            int nb, int npool) {
    const int i = blockIdx.x * 256 + threadIdx.x;
    if (i < nb) bcur[i] = 0;
    const int j = i - nb;
    if (j >= 0 && j < npool) pooled[j] = 0.0f;
    if (i < 128 * 128) {                       // Wt1[c][k] = W1[k][c]
        int k = i & 127, c = i >> 7;
        Wt1[c * 128 + k] = (_Float16)W1[k * 128 + c];
    }
    if (i < 64 * 128) {                        // Wt2[c][k] = W2[k][c]
        int k = i & 127, c = i >> 7;
        Wt2[c * 128 + k] = (_Float16)W2[k * 64 + c];
    }
}

// ---------------- bucketed CSR build ----------------

// pass 1: scatter edges into per-bucket regions, packed src | ((dst&255)<<18)
__global__ __launch_bounds__(256) void bin_scatter(const int* __restrict__ esrc,
                                                   const int* __restrict__ edst,
                                                   int ne, int nb,
                                                   int* __restrict__ bucket_cursor,
                                                   int* __restrict__ ebin) {
    __shared__ int lcnt[256];
    __shared__ int lcur[256];
    const int tid = threadIdx.x;
    const int e0 = blockIdx.x * 8192;
    int dcache[32];                     // edst cached in regs across phases
    lcnt[tid] = 0;
    __syncthreads();
    #pragma unroll
    for (int k = 0; k < 32; k++) {
        int e = e0 + k * 256 + tid;
        dcache[k] = (e < ne) ? edst[e] : -1;
        if (dcache[k] >= 0) atomicAdd(&lcnt[dcache[k] >> 8], 1);
    }
    __syncthreads();
    if (tid < nb && lcnt[tid] > 0)
        lcur[tid] = atomicAdd(&bucket_cursor[tid], lcnt[tid]);
    __syncthreads();
    #pragma unroll
    for (int k = 0; k < 32; k++) {
        int d = dcache[k];
        if (d >= 0) {
            int e = e0 + k * 256 + tid;
            int b = d >> 8;
            int p = atomicAdd(&lcur[b], 1);          // relative position
            if (p < BCAP)                            // capacity guard
                ebin[b * BCAP + p] = esrc[e] | ((d & 255) << 18); // src < 2^17
        }
    }
}

// pass 2: one block per bucket: LDS counts -> scan -> nodeinfo+dinv -> ticket fill
__global__ __launch_bounds__(256) void bucket_csr(const int* __restrict__ ebin,
                                                  const int* __restrict__ bucket_cursor,
                                                  int n_nodes,
                                                  int* __restrict__ csr,
                                                  int2* __restrict__ nodeinfo,
                                                  float* __restrict__ dinv) {
    __shared__ int lcnt[256];
    __shared__ int lscan[256];
    __shared__ int lcur[256];
    const int b = blockIdx.x;
    const int tid = threadIdx.x;
    const int ebeg = b * BCAP;
    int cnt_b = bucket_cursor[b];
    if (cnt_b > BCAP) cnt_b = BCAP;
    const int eend = ebeg + cnt_b;
    lcnt[tid] = 0;
    __syncthreads();
    for (int e = ebeg + tid; e < eend; e += 256)
        atomicAdd(&lcnt[(ebin[e] >> 18) & 255], 1);
    __syncthreads();
    int v = lcnt[tid];
    lscan[tid] = v;
    __syncthreads();
    for (int off = 1; off < 256; off <<= 1) {
        int u = (tid >= off) ? lscan[tid - off] : 0;
        __syncthreads();
        lscan[tid] += u;
        __syncthreads();
    }
    const int start = ebeg + (lscan[tid] - v);   // exclusive scan position
    const int node = (b << 8) + tid;
    if (node < n_nodes) {
        nodeinfo[node] = make_int2(start, v);
        dinv[node] = (float)(1.0 / sqrt((double)(v + 1)));  // +1 self loop
    }
    lcur[tid] = start;
    __syncthreads();
    for (int e = ebeg + tid; e < eend; e += 256) {
        int pk = ebin[e];
        int p = atomicAdd(&lcur[(pk >> 18) & 255], 1);
        csr[p] = pk & 0x3FFFF;
    }
}

// ---------------- LDS-free direct-fragment MFMA GEMM ----------------
// t_out[row, c] = fp16( (A[row,:128] @ W[:128,c]) * dinv[row] )
// 256 thr = 4 waves; each wave owns 32 rows. A-fragments (8 contiguous k/lane)
// loaded once into regs; col-tiles looped reusing them. B-fragments are half8
// loads from Wt[col][k] (fp16, 16-32 KB, L1-resident). No LDS, no barriers.
template <int FOUT, bool A_F16>
__global__ __launch_bounds__(256) void gemm_direct(const void* __restrict__ Aptr,
                                                   const _Float16* __restrict__ Wt,
                                                   const float* __restrict__ dinv,
                                                   _Float16* __restrict__ out, int n) {
    const int wv = threadIdx.x >> 6;
    const int lane = threadIdx.x & 63;
    const int row0 = blockIdx.x * 128 + wv * 32;   // this wave's 32 rows
    const int r16 = lane & 15;
    const int kb = (lane >> 4) * 8;                // k-offset within 32-k step

    // A fragments: [mi][ks], row = row0 + mi*16 + r16, k = ks*32 + kb .. +7
    half8 afrag[2][4];
    #pragma unroll
    for (int mi = 0; mi < 2; mi++) {
        const int grow = row0 + mi * 16 + r16;
        #pragma unroll
        for (int ks = 0; ks < 4; ks++) {
            if constexpr (A_F16) {
                half8 v = {};
                if (grow < n)
                    v = *(const half8*)((const _Float16*)Aptr + (size_t)grow * 128 + ks * 32 + kb);
                afrag[mi][ks] = v;
            } else {
                float4 v0 = {0.f, 0.f, 0.f, 0.f}, v1 = {0.f, 0.f, 0.f, 0.f};
                if (grow < n) {
                    const float* p = (const float*)Aptr + (size_t)grow * 128 + ks * 32 + kb;
                    v0 = *(const float4*)(p);
                    v1 = *(const float4*)(p + 4);
                }
                afrag[mi][ks] = half8{(_Float16)v0.x, (_Float16)v0.y, (_Float16)v0.z, (_Float16)v0.w,
                                      (_Float16)v1.x, (_Float16)v1.y, (_Float16)v1.z, (_Float16)v1.w};
            }
        }
    }

    #pragma unroll
    for (int ct = 0; ct < FOUT / 64; ct++) {
        const int col0 = ct * 64;
        f32x4 acc[2][4] = {};
        #pragma unroll
        for (int ks = 0; ks < 4; ks++) {
            #pragma unroll
            for (int nj = 0; nj < 4; nj++) {
                half8 b = *(const half8*)(Wt + (size_t)(col0 + nj * 16 + r16) * 128 + ks * 32 + kb);
                acc[0][nj] = __builtin_amdgcn_mfma_f32_16x16x32_f16(afrag[0][ks], b, acc[0][nj], 0, 0, 0);
                acc[1][nj] = __builtin_amdgcn_mfma_f32_16x16x32_f16(afrag[1][ks], b, acc[1][nj], 0, 0, 0);
            }
        }
        // C/D layout: col = lane&15, row = (lane>>4)*4 + reg
        #pragma unroll
        for (int mi = 0; mi < 2; mi++) {
            const int gr0 = row0 + mi * 16 + (lane >> 4) * 4;
            #pragma unroll
            for (int r = 0; r < 4; r++) {
                const int grow = gr0 + r;
                if (grow < n) {
                    const float s = dinv[grow];
                    #pragma unroll
                    for (int nj = 0; nj < 4; nj++) {
                        out[(size_t)grow * FOUT + col0 + nj * 16 + r16] =
                            (_Float16)(acc[mi][nj][r] * s);
                    }
                }
            }
        }
    }
}

// ---------------- layer-1 aggregation: fp16 row-sum gather, 8-deep ----------------
// h1[i] = fp16( relu( (sum_{s in N(i) u {i}} t1[s]) * dinv[i] + b1 ) )
__global__ __launch_bounds__(256) void aggregate_l1(const __half* __restrict__ t,
                                                    const float* __restrict__ dinv,
                                                    const int2* __restrict__ nodeinfo,
                                                    const int* __restrict__ csr_src,
                                                    const float* __restrict__ bias,
                                                    __half* __restrict__ outp, int n) {
    constexpr int F = 128;
    const int wv = threadIdx.x >> 6;
    const int lane = threadIdx.x & 63;
    const int i = blockIdx.x * 4 + wv;
    if (i >= n) return;
    const float di = dinv[i];
    const int2 ni = nodeinfo[i];
    const int e0 = ni.x, e1 = ni.x + ni.y;

    float2 a0, a1 = {0.f, 0.f}, a2 = {0.f, 0.f}, a3 = {0.f, 0.f};
    a0 = __half22float2(((const __half2*)(t + (size_t)i * F))[lane]);  // self
    int e = e0;
    for (; e + 8 <= e1; e += 8) {     // 8 row-gathers in flight
        int s0 = csr_src[e + 0], s1 = csr_src[e + 1], s2 = csr_src[e + 2], s3 = csr_src[e + 3];
        int s4 = csr_src[e + 4], s5 = csr_src[e + 5], s6 = csr_src[e + 6], s7 = csr_src[e + 7];
        float2 v0 = __half22float2(((const __half2*)(t + (size_t)s0 * F))[lane]);
        float2 v1 = __half22float2(((const __half2*)(t + (size_t)s1 * F))[lane]);
        float2 v2 = __half22float2(((const __half2*)(t + (size_t)s2 * F))[lane]);
        float2 v3 = __half22float2(((const __half2*)(t + (size_t)s3 * F))[lane]);
        float2 v4 = __half22float2(((const __half2*)(t + (size_t)s4 * F))[lane]);
        float2 v5 = __half22float2(((const __half2*)(t + (size_t)s5 * F))[lane]);
        float2 v6 = __half22float2(((const __half2*)(t + (size_t)s6 * F))[lane]);
        float2 v7 = __half22float2(((const __half2*)(t + (size_t)s7 * F))[lane]);
        a0.x += v0.x + v4.x; a0.y += v0.y + v4.y;
        a1.x += v1.x + v5.x; a1.y += v1.y + v5.y;
        a2.x += v2.x + v6.x; a2.y += v2.y + v6.y;
        a3.x += v3.x + v7.x; a3.y += v3.y + v7.y;
    }
    for (; e + 4 <= e1; e += 4) {
        int s0 = csr_src[e + 0], s1 = csr_src[e + 1], s2 = csr_src[e + 2], s3 = csr_src[e + 3];
        float2 v0 = __half22float2(((const __half2*)(t + (size_t)s0 * F))[lane]);
        float2 v1 = __half22float2(((const __half2*)(t + (size_t)s1 * F))[lane]);
        float2 v2 = __half22float2(((const __half2*)(t + (size_t)s2 * F))[lane]);
        float2 v3 = __half22float2(((const __half2*)(t + (size_t)s3 * F))[lane]);
        a0.x += v0.x; a0.y += v0.y;
        a1.x += v1.x; a1.y += v1.y;
        a2.x += v2.x; a2.y += v2.y;
        a3.x += v3.x; a3.y += v3.y;
    }
    for (; e < e1; e++) {
        int s = csr_src[e];
        float2 v = __half22float2(((const __half2*)(t + (size_t)s * F))[lane]);
        a0.x += v.x; a0.y += v.y;
    }
    float2 b = ((const float2*)bias)[lane];
    float rx = (a0.x + a1.x + a2.x + a3.x) * di + b.x;
    float ry = (a0.y + a1.y + a2.y + a3.y) * di + b.y;
    rx = fmaxf(rx, 0.f); ry = fmaxf(ry, 0.f);
    ((__half2*)(outp + (size_t)i * F))[lane] = __floats2half2_rn(rx, ry);
}

// ---------------- layer-2 aggregation fused with pooled accumulation ----------------
// pooled_sums[batch[i]][f] += (sum_{s in N(i) u {i}} t2[s][f]) * dinv[i]
__global__ __launch_bounds__(256) void aggregate_pool(const __half* __restrict__ t,
                                                      const float* __restrict__ dinv,
                                                      const int2* __restrict__ nodeinfo,
                                                      const int* __restrict__ csr_src,
                                                      const int* __restrict__ batch,
                                                      float* __restrict__ pooled_sums, int n) {
    constexpr int F = 64;
    const int wv = threadIdx.x >> 6;
    const int lane = threadIdx.x & 63;
    const int i = blockIdx.x * 4 + wv;
    if (i >= n) return;
    const float di = dinv[i];
    const int2 ni = nodeinfo[i];
    const int e0 = ni.x, e1 = ni.x + ni.y;

    float a0, a1 = 0.f, a2 = 0.f, a3 = 0.f;
    a0 = __half2float(t[(size_t)i * F + lane]);  // self
    int e = e0;
    for (; e + 8 <= e1; e += 8) {     // 8 row-gathers in flight
        int s0 = csr_src[e + 0], s1 = csr_src[e + 1], s2 = csr_src[e + 2], s3 = csr_src[e + 3];
        int s4 = csr_src[e + 4], s5 = csr_src[e + 5], s6 = csr_src[e + 6], s7 = csr_src[e + 7];
        float v0 = __half2float(t[(size_t)s0 * F + lane]);
        float v1 = __half2float(t[(size_t)s1 * F + lane]);
        float v2 = __half2float(t[(size_t)s2 * F + lane]);
        float v3 = __half2float(t[(size_t)s3 * F + lane]);
        float v4 = __half2float(t[(size_t)s4 * F + lane]);
        float v5 = __half2float(t[(size_t)s5 * F + lane]);
        float v6 = __half2float(t[(size_t)s6 * F + lane]);
        float v7 = __half2float(t[(size_t)s7 * F + lane]);
        a0 += v0 + v4; a1 += v1 + v5; a2 += v2 + v6; a3 += v3 + v7;
    }
    for (; e + 4 <= e1; e += 4) {
        int s0 = csr_src[e + 0], s1 = csr_src[e + 1], s2 = csr_src[e + 2], s3 = csr_src[e + 3];
        a0 += __half2float(t[(size_t)s0 * F + lane]);
        a1 += __half2float(t[(size_t)s1 * F + lane]);
        a2 += __half2float(t[(size_t)s2 * F + lane]);
        a3 += __half2float(t[(size_t)s3 * F + lane]);
    }
    for (; e < e1; e++) {
        a0 += __half2float(t[(size_t)csr_src[e] * F + lane]);
    }
    float r = (a0 + a1 + a2 + a3) * di;
    const int g = batch[i];
    atomicAdd(&pooled_sums[(size_t)g * F + lane], r);
}

// ---------------- classifier: /cnt + b2, then @Wl + bl ----------------
__global__ __launch_bounds__(64) void classify(const float* __restrict__ pooled_sums,
                                               const int* __restrict__ batch, int n,
                                               const float* __restrict__ b2,
                                               const float* __restrict__ Wl,
                                               const float* __restrict__ bl,
                                               float* __restrict__ out) {
    __shared__ float pr[64];
    const int g = blockIdx.x;
    const int lane = threadIdx.x;
    int lo = 0, hi = n;
    while (lo < hi) { int mid = (lo + hi) >> 1; if (batch[mid] < g) lo = mid + 1; else hi = mid; }
    const int start = lo;
    hi = n;
    while (lo < hi) { int mid = (lo + hi) >> 1; if (batch[mid] < g + 1) lo = mid + 1; else hi = mid; }
    const float cnt = (float)(lo - start);
    float p = pooled_sums[(size_t)g * 64 + lane] / fmaxf(cnt, 1.0f) + b2[lane];
    pr[lane] = p;
    __syncthreads();
    float acc = bl[lane];
    #pragma unroll 8
    for (int k = 0; k < 64; k++) acc += pr[k] * Wl[k * 64 + lane];
    out[(size_t)g * 64 + lane] = acc;
}

// ---------------- launch ----------------

extern "C" void kernel_launch(void* const* d_in, const int* in_sizes, int n_in,
                              void* d_out, int out_size, void* d_ws, size_t ws_size,
                              hipStream_t stream) {
    const float* x    = (const float*)d_in[0];
    const int*   eidx = (const int*)d_in[1];
    const int*   batch= (const int*)d_in[2];
    const float* W1   = (const float*)d_in[3];
    const float* b1   = (const float*)d_in[4];
    const float* W2   = (const float*)d_in[5];
    const float* b2   = (const float*)d_in[6];
    const float* Wl   = (const float*)d_in[7];
    const float* bl   = (const float*)d_in[8];
    float* out = (float*)d_out;

    const int n_nodes  = in_sizes[0] / FEAT1;     // 50000
    const int n_edges  = in_sizes[1] / 2;         // 800000
    const int n_graphs = out_size / FEAT2;        // 512
    const int* esrc = eidx;
    const int* edst = eidx + n_edges;
    const int nb = (n_nodes + 255) >> 8;          // 196 buckets
    const int npool = n_graphs * FEAT2;           // 32768

    // workspace layout
    char* ws = (char*)d_ws;
    size_t off = 0;
    auto alloc = [&](size_t bytes) -> void* {
        void* p = ws + off;
        off += (bytes + 255) & ~(size_t)255;
        return p;
    };
    _Float16* t1     = (_Float16*)alloc((size_t)n_nodes * FEAT1 * 2); // fp16 scaled table (reused as t2)
    __half*   h1h    = (__half*)alloc((size_t)n_nodes * FEAT1 * 2);   // fp16 h1 (agg1 out, gemm2 in)
    float*    dinv   = (float*)alloc((size_t)n_nodes * 4);
    int2*   nodeinfo = (int2*)alloc((size_t)n_nodes * 8);
    int*    bcur     = (int*)alloc((size_t)nb * 4);
    float*  pooled   = (float*)alloc((size_t)npool * 4);
    _Float16* Wt1    = (_Float16*)alloc(128 * 128 * 2);
    _Float16* Wt2    = (_Float16*)alloc(64 * 128 * 2);
    int*    ebin     = (int*)alloc((size_t)nb * BCAP * 4);
    int*    csr      = (int*)alloc((size_t)nb * BCAP * 4);

    const int nrb = (n_nodes + 127) / 128;        // 391 row-tiles

    // 1. prep (zero bcur+pooled, transpose W1/W2 to fp16); bucketed CSR build
    prep<<<(nb + npool + 255) / 256, 256, 0, stream>>>(W1, W2, Wt1, Wt2, bcur, pooled, nb, npool);
    bin_scatter<<<(n_edges + 8191) / 8192, 256, 0, stream>>>(esrc, edst, n_edges, nb, bcur, ebin);
    bucket_csr<<<nb, 256, 0, stream>>>(ebin, bcur, n_nodes, csr, nodeinfo, dinv);

    // 2. layer 1: t1 = fp16((x @ W1) * dinv) ; h1 = fp16(relu(agg(t1)*dinv + b1))
    gemm_direct<FEAT1, false><<<nrb, 256, 0, stream>>>(x, Wt1, dinv, t1, n_nodes);
    aggregate_l1<<<(n_nodes + 3) / 4, 256, 0, stream>>>(
        (const __half*)t1, dinv, nodeinfo, csr, b1, h1h, n_nodes);

    // 3. layer 2: t2 = fp16((h1 @ W2) * dinv) ; pooled_sums += agg(t2)*dinv per graph
    gemm_direct<FEAT2, true><<<nrb, 256, 0, stream>>>(h1h, Wt2, dinv, t1, n_nodes);
    aggregate_pool<<<(n_nodes + 3) / 4, 256, 0, stream>>>(
        (const __half*)t1, dinv, nodeinfo, csr, batch, pooled, n_nodes);

    // 4. classifier: /cnt + b2, @Wl + bl
    classify<<<n_graphs, 64, 0, stream>>>(pooled, batch, n_nodes, b2, Wl, bl, out);
}